// Round 3
// baseline (226.278 us; speedup 1.0000x reference)
//
#include <hip/hip_runtime.h>
#include <hip/hip_bf16.h>

typedef __attribute__((ext_vector_type(8))) short bf16x8;
typedef __attribute__((ext_vector_type(4))) float f32x4;
typedef unsigned short u16;
typedef unsigned int u32;

__device__ __forceinline__ u16 f2bf(float f) {
    u32 u = __float_as_uint(f);
    u = (u + 0x7FFFu + ((u >> 16) & 1u)) >> 16;
    return (u16)u;
}

#define GLDS16(g, l) __builtin_amdgcn_global_load_lds( \
    (const __attribute__((address_space(1))) u32*)(g), \
    (__attribute__((address_space(3))) u32*)(l), 16, 0, 0)

// ---------- centers: cn = c/||c|| bf16, granule layout [b][kb24][dc4][k256][8] ----------
__global__ __launch_bounds__(256) void k_centers(const float* __restrict__ c, u16* __restrict__ cn) {
    int bid = blockIdx.x;                      // 512 blocks, 4 rows each
    int w = threadIdx.x >> 6, lane = threadIdx.x & 63;
    int row = (bid << 2) + w;                  // b*256 + k
    int b = row >> 8;
    __shared__ u16 rb[4][800];                 // padded row buffer
    const float* src = c + (size_t)row * 768;
    float v[12]; float ss = 0.f;
#pragma unroll
    for (int j = 0; j < 12; ++j) { v[j] = src[lane + (j << 6)]; ss += v[j] * v[j]; }
#pragma unroll
    for (int m = 1; m < 64; m <<= 1) ss += __shfl_xor(ss, m, 64);
    float inv = 1.0f / sqrtf(ss);
#pragma unroll
    for (int j = 0; j < 12; ++j) rb[w][lane + (j << 6)] = f2bf(v[j] * inv);
    __syncthreads();
    int t = threadIdx.x;
    int k0 = (bid << 2) & 255;
#pragma unroll
    for (int p = 0; p < 2; ++p) {
        int idx = (p << 8) + t;
        if (idx < 384) {
            int g = idx >> 2, kr = idx & 3;
            uint4 val = *reinterpret_cast<const uint4*>(&rb[kr][g << 3]);
            int kb = g >> 2, dc = g & 3;
            size_t o = ((((size_t)(b * 24 + kb) << 2) + dc) << 8) + k0 + kr;
            *reinterpret_cast<uint4*>(cn + (o << 3)) = val;
        }
    }
}

// ---------- GEMM1: cos + softmax + probT + den + xT emission ----------
__global__ __launch_bounds__(512, 2) void k_gemm1(const float* __restrict__ x, const u16* __restrict__ cn,
                                                  u16* __restrict__ probT, u16* __restrict__ xT,
                                                  float* __restrict__ den) {
    const int b = blockIdx.y;
    const int n0 = blockIdx.x << 8;            // 256-token tile
    const int t = threadIdx.x;
    const int wave = t >> 6, lane = t & 63;
    const int lr = lane & 15, lg = lane >> 4;
    const int wm = wave >> 1, wk = wave & 1;   // token quarter / k half

    __shared__ u16 Ab[2][4][256][8];           // 32 KB  [buf][dc][row^swz][8]
    __shared__ u16 Bb[2][4][256][8];           // 32 KB
    __shared__ u16 T[256][80];                 // 40 KB transpose staging
    __shared__ float inv_s[256];
    __shared__ float sums[256];
    __shared__ float denp[256];

    f32x4 acc[4][8];
#pragma unroll
    for (int m = 0; m < 4; ++m)
#pragma unroll
        for (int f = 0; f < 8; ++f) acc[m][f] = (f32x4){0.f, 0.f, 0.f, 0.f};

    const float* xb = x + ((size_t)b * 8192 + n0) * 768;
    const char* cnb = (const char*)(cn + ((size_t)b * 24 * 4 * 256 * 8));
    u16* xTb = xT + (size_t)b * 768 * 8192;

    const int arow = t >> 2;                   // 0..127
    const int adc = t & 3;
    const float* ap0 = xb + (size_t)arow * 768 + (adc << 3);
    const float* ap1 = ap0 + (size_t)128 * 768;

    float sq0 = 0.f, sq1 = 0.f;
    float4 xa0, xa1, xb0, xb1;

    auto issueA = [&](int kb) {
        const float* p0 = ap0 + (kb << 5);
        xa0 = *reinterpret_cast<const float4*>(p0);
        xa1 = *reinterpret_cast<const float4*>(p0 + 4);
        const float* p1 = ap1 + (kb << 5);
        xb0 = *reinterpret_cast<const float4*>(p1);
        xb1 = *reinterpret_cast<const float4*>(p1 + 4);
    };
    auto issueB = [&](int buf, int kb) {
        const char* srcb = cnb + (size_t)kb * 16384 + (wave << 10) + (lane << 4);
        char* dstb = (char*)&Bb[buf][0][0][0] + (wave << 10);
        GLDS16(srcb, dstb);
        GLDS16(srcb + 8192, dstb + 8192);
    };
    auto procA = [&](int buf, int kb) {
#pragma unroll
        for (int p = 0; p < 2; ++p) {
            float4 A = p ? xb0 : xa0;
            float4 B2 = p ? xb1 : xa1;
            float s2 = A.x*A.x + A.y*A.y + A.z*A.z + A.w*A.w
                     + B2.x*B2.x + B2.y*B2.y + B2.z*B2.z + B2.w*B2.w;
            if (p) sq1 += s2; else sq0 += s2;
            u32 g0 = (u32)f2bf(A.x)  | ((u32)f2bf(A.y)  << 16);
            u32 g1 = (u32)f2bf(A.z)  | ((u32)f2bf(A.w)  << 16);
            u32 g2 = (u32)f2bf(B2.x) | ((u32)f2bf(B2.y) << 16);
            u32 g3 = (u32)f2bf(B2.z) | ((u32)f2bf(B2.w) << 16);
            int row = (p << 7) + arow;
            *reinterpret_cast<uint4*>(&Ab[buf][adc][row ^ (adc << 1)][0]) = make_uint4(g0, g1, g2, g3);
            // 8x8 u16 transpose among lanes {lane&3 == adc, j = (lane>>2)&7}
            u32 a0 = g0, a1 = g1, a2 = g2, a3 = g3;
            {   // swap 4x4 blocks: lane-bit4
                bool hi = (lane & 16) != 0;
                u32 t0 = hi ? a0 : a2, t1 = hi ? a1 : a3;
                u32 s0 = (u32)__shfl_xor((int)t0, 16, 64);
                u32 s1 = (u32)__shfl_xor((int)t1, 16, 64);
                a0 = hi ? s0 : a0; a1 = hi ? s1 : a1;
                a2 = hi ? a2 : s0; a3 = hi ? a3 : s1;
            }
            {   // swap 2x2 blocks: lane-bit3
                bool h1 = (lane & 8) != 0;
                u32 t0 = h1 ? a0 : a1, t1 = h1 ? a2 : a3;
                u32 s0 = (u32)__shfl_xor((int)t0, 8, 64);
                u32 s1 = (u32)__shfl_xor((int)t1, 8, 64);
                a0 = h1 ? s0 : a0; a1 = h1 ? a1 : s0;
                a2 = h1 ? s1 : a2; a3 = h1 ? a3 : s1;
            }
            {   // u16 swap: lane-bit2
                bool h0 = (lane & 4) != 0;
#pragma unroll
                for (int m = 0; m < 4; ++m) {
                    u32* am = m == 0 ? &a0 : m == 1 ? &a1 : m == 2 ? &a2 : &a3;
                    u32 s = (u32)__shfl_xor((int)*am, 4, 64);
                    *am = h0 ? ((*am & 0xFFFF0000u) | (s >> 16))
                             : ((*am & 0x0000FFFFu) | (s << 16));
                }
            }
            int j = (lane >> 2) & 7;
            int dg = (kb << 5) + (adc << 3) + j;
            int R0 = (t >> 5) << 3;
            *reinterpret_cast<uint4*>(xTb + ((size_t)dg << 13) + n0 + (p << 7) + R0)
                = make_uint4(a0, a1, a2, a3);
        }
    };

    // prologue
    issueA(0);
    issueB(0, 0);
    procA(0, 0);
    __syncthreads();

    for (int kb = 0; kb < 24; ++kb) {
        int cur = kb & 1, nxt = cur ^ 1;
        if (kb < 23) { issueA(kb + 1); issueB(nxt, kb + 1); }
        bf16x8 a[4];
#pragma unroll
        for (int m = 0; m < 4; ++m) {
            int tok = (wm << 6) + (m << 4) + lr;
            a[m] = *reinterpret_cast<const bf16x8*>(&Ab[cur][lg][tok ^ (lg << 1)][0]);
        }
#pragma unroll
        for (int f = 0; f < 8; ++f) {
            bf16x8 bf = *reinterpret_cast<const bf16x8*>(&Bb[cur][lg][(wk << 7) + (f << 4) + lr][0]);
#pragma unroll
            for (int m = 0; m < 4; ++m)
                acc[m][f] = __builtin_amdgcn_mfma_f32_16x16x32_bf16(a[m], bf, acc[m][f], 0, 0, 0);
        }
        if (kb < 23) procA(nxt, kb + 1);
        __syncthreads();
    }

    // row norms
    sq0 += __shfl_xor(sq0, 1, 64); sq0 += __shfl_xor(sq0, 2, 64);
    sq1 += __shfl_xor(sq1, 1, 64); sq1 += __shfl_xor(sq1, 2, 64);
    if ((t & 3) == 0) {
        inv_s[arow] = 1.0f / sqrtf(sq0);
        inv_s[128 + arow] = 1.0f / sqrtf(sq1);
    }
    if (t < 256) { sums[t] = 0.f; denp[t] = 0.f; }
    __syncthreads();

    float iv[4][4];
#pragma unroll
    for (int m = 0; m < 4; ++m) {
        f32x4 v = *reinterpret_cast<const f32x4*>(&inv_s[(wm << 6) + (m << 4) + (lg << 2)]);
#pragma unroll
        for (int r = 0; r < 4; ++r) iv[m][r] = v[r];
    }

    // exp (logits bounded by ~1: no max-subtract) + row sums over K
    float rp[4][4];
#pragma unroll
    for (int m = 0; m < 4; ++m)
#pragma unroll
        for (int r = 0; r < 4; ++r) rp[m][r] = 0.f;
#pragma unroll
    for (int m = 0; m < 4; ++m)
#pragma unroll
        for (int f = 0; f < 8; ++f)
#pragma unroll
            for (int r = 0; r < 4; ++r) {
                float e = __expf(acc[m][f][r] * iv[m][r]);
                acc[m][f][r] = e; rp[m][r] += e;
            }
#pragma unroll
    for (int m = 0; m < 4; ++m)
#pragma unroll
        for (int r = 0; r < 4; ++r) {
#pragma unroll
            for (int msk = 1; msk < 16; msk <<= 1) rp[m][r] += __shfl_xor(rp[m][r], msk, 64);
        }
    if (lr == 0) {
#pragma unroll
        for (int m = 0; m < 4; ++m)
#pragma unroll
            for (int r = 0; r < 4; ++r)
                atomicAdd(&sums[(wm << 6) + (m << 4) + (lg << 2) + r], rp[m][r]);
    }
    __syncthreads();

    float rs[4][4];
#pragma unroll
    for (int m = 0; m < 4; ++m) {
        f32x4 v = *reinterpret_cast<const f32x4*>(&sums[(wm << 6) + (m << 4) + (lg << 2)]);
#pragma unroll
        for (int r = 0; r < 4; ++r) rs[m][r] = 1.0f / v[r];
    }

    float dp[8];
#pragma unroll
    for (int f = 0; f < 8; ++f) dp[f] = 0.f;
#pragma unroll
    for (int m = 0; m < 4; ++m)
#pragma unroll
        for (int f = 0; f < 8; ++f)
#pragma unroll
            for (int r = 0; r < 4; ++r) {
                float pr = acc[m][f][r] * rs[m][r];
                acc[m][f][r] = pr; dp[f] += pr;
            }
#pragma unroll
    for (int f = 0; f < 8; ++f) {
        dp[f] += __shfl_xor(dp[f], 16, 64);
        dp[f] += __shfl_xor(dp[f], 32, 64);
    }
    if (lg == 0) {
#pragma unroll
        for (int f = 0; f < 8; ++f) atomicAdd(&denp[(wk << 7) + (f << 4) + lr], dp[f]);
    }

    // probT writeout in 4 token-chunks via LDS transpose
    u16* pTb = probT + (size_t)b * 256 * 8192 + n0;
#pragma unroll
    for (int c = 0; c < 4; ++c) {
        __syncthreads();
        if (wm == c) {
#pragma unroll
            for (int f = 0; f < 8; ++f)
#pragma unroll
                for (int m = 0; m < 4; ++m)
                    *reinterpret_cast<ushort4*>(&T[(wk << 7) + (f << 4) + lr][(m << 4) + (lg << 2)]) =
                        make_ushort4(f2bf(acc[m][f][0]), f2bf(acc[m][f][1]),
                                     f2bf(acc[m][f][2]), f2bf(acc[m][f][3]));
        }
        __syncthreads();
#pragma unroll
        for (int i = 0; i < 4; ++i) {
            int ii = (i << 9) + t;
            int row = ii >> 3, ch = ii & 7;
            *reinterpret_cast<uint4*>(pTb + (size_t)row * 8192 + (c << 6) + (ch << 3)) =
                *reinterpret_cast<const uint4*>(&T[row][ch << 3]);
        }
    }
    __syncthreads();
    if (t < 256) atomicAdd(&den[(b << 8) + t], denp[t]);
}

// ---------- GEMM2: num_part[s][b][k][d] = sum_n prob[k][n] * xT[d][n], pure-register ----------
__global__ __launch_bounds__(256) void k_gemm2(const u16* __restrict__ probT, const u16* __restrict__ xT,
                                               float* __restrict__ num_part) {
    int bid = blockIdx.x;                      // 768
    int xcd = bid & 7, idx = bid >> 3;
    int orig = xcd * 96 + idx;
    int dt = orig % 12, sb = orig / 12;        // 12 d-tiles grouped per XCD
    int s = sb >> 3, b = sb & 7;
    int d0 = dt << 6;

    const int t = threadIdx.x;
    const int wave = t >> 6, lane = t & 63;
    const int lr = lane & 15, lg = lane >> 4;
    const int kq = wave << 6;

    f32x4 acc[4][4];
#pragma unroll
    for (int m = 0; m < 4; ++m)
#pragma unroll
        for (int f = 0; f < 4; ++f) acc[m][f] = (f32x4){0.f, 0.f, 0.f, 0.f};

    const u16* pA = probT + (size_t)b * 256 * 8192;
    const u16* pX = xT + (size_t)b * 768 * 8192;
    const int nbase = (s << 10) + (lg << 3);

#pragma unroll 2
    for (int it = 0; it < 32; ++it) {
        int nb = nbase + (it << 5);
        bf16x8 a[4], bb[4];
#pragma unroll
        for (int m = 0; m < 4; ++m)
            a[m] = *reinterpret_cast<const bf16x8*>(pA + (((size_t)(kq + (m << 4) + lr)) << 13) + nb);
#pragma unroll
        for (int f = 0; f < 4; ++f)
            bb[f] = *reinterpret_cast<const bf16x8*>(pX + (((size_t)(d0 + (f << 4) + lr)) << 13) + nb);
#pragma unroll
        for (int m = 0; m < 4; ++m)
#pragma unroll
            for (int f = 0; f < 4; ++f)
                acc[m][f] = __builtin_amdgcn_mfma_f32_16x16x32_bf16(a[m], bb[f], acc[m][f], 0, 0, 0);
    }

    float* np = num_part + ((size_t)(s * 8 + b)) * 256 * 768;
#pragma unroll
    for (int m = 0; m < 4; ++m) {
        int kr = kq + (m << 4) + (lg << 2);
#pragma unroll
        for (int r = 0; r < 4; ++r)
#pragma unroll
            for (int f = 0; f < 4; ++f)
                np[(size_t)(kr + r) * 768 + d0 + (f << 4) + lr] = acc[m][f][r];
    }
}

// ---------- finalize ----------
__global__ __launch_bounds__(256) void k_final(const float* __restrict__ num_part, const float* __restrict__ den,
                                               float* __restrict__ out) {
    int i = blockIdx.x * 256 + threadIdx.x;
    float sum = 0.f;
#pragma unroll
    for (int ss = 0; ss < 8; ++ss) sum += num_part[(size_t)ss * 1572864 + i];
    out[i] = sum / (den[i / 768] + 1e-8f);
}

extern "C" void kernel_launch(void* const* d_in, const int* in_sizes, int n_in,
                              void* d_out, int out_size, void* d_ws, size_t ws_size,
                              hipStream_t stream) {
    const float* x = (const float*)d_in[0];
    const float* centers = (const float*)d_in[1];
    float* out = (float*)d_out;
    char* ws = (char*)d_ws;
    u16* cn      = (u16*)ws;                         //   3,145,728 B
    u16* probT   = (u16*)(ws + 3145728);             //  33,554,432 B
    float* den   = (float*)(ws + 36700160);          //       8,192 B
    u16* xT      = (u16*)(ws + 36708352);            // 100,663,296 B
    float* numpt = (float*)(ws + 137371648);         //  50,331,648 B  (total ~188 MB)

    hipMemsetAsync(den, 0, 8192, stream);
    k_centers<<<512, 256, 0, stream>>>(centers, cn);
    k_gemm1<<<dim3(32, 8), 512, 0, stream>>>(x, cn, probT, xT, den);
    k_gemm2<<<768, 256, 0, stream>>>(probT, xT, numpt);
    k_final<<<6144, 256, 0, stream>>>(numpt, den, out);
}